// Round 3
// baseline (483134.473 us; speedup 1.0000x reference)
//
#include <hip/hip_runtime.h>
#include <math.h>
#include <float.h>

// Problem: B=256, H=1024, I=1, O=512, T=512. Autoregressive LSTM + greedy head.
#define NB 256
#define NH 1024
#define NO 512
#define NT 512

// ---------------- workspace layout (float offsets) ----------------
// hT4 layout: [q=u>>2][b][j=u&3]  (256K floats per buffer). Block blk owns q=blk.
#define OFF_HT4_0 0
#define OFF_HT4_1 (256*1024)
#define OFF_WLT   (2*256*1024)            // packed w_lin: [u/4][o][4] = 512K floats
#define OFF_PART  (OFF_WLT + 512*1024)    // argmax partials [B][16][{val,idx}] = 8192
#define OFF_BAR   (OFF_PART + 8192)       // barrier: cnt8 @ dword i*16, master @128, gen @160

__device__ __forceinline__ float sigf(float x) { return 1.f / (1.f + expf(-x)); }

#define FMA4(A, W, H4) \
  A = fmaf((W).x, (H4).x, A); A = fmaf((W).y, (H4).y, A); \
  A = fmaf((W).z, (H4).z, A); A = fmaf((W).w, (H4).w, A);

// ---------------------------------------------------------------------------
// Init: pack h0=z into hT4 ping, pack w_lin into [u/4][o][4], seed argmax
// partials to (-FLT_MAX, 0) so step 0 sees xin = 0, zero barrier state.
// (c-state now lives in registers of the persistent kernel.)
// ---------------------------------------------------------------------------
__global__ void k_init(const float* __restrict__ z, const float* __restrict__ w_lin,
                       float* __restrict__ ws) {
  int idx = blockIdx.x * 256 + threadIdx.x;
  if (idx < 512 * 1024) {                 // wltp[uq*2048 + o*4 + j] = w_lin[o][4uq+j]
    int j = idx & 3, o = (idx >> 2) & 511, uq = idx >> 11;
    ws[OFF_WLT + idx] = w_lin[o * 1024 + (uq << 2) + j];
  }
  if (idx < 256 * 1024) {                 // hT4[q][b][j] = z[b][4q+j]
    int q = idx >> 10, r = idx & 1023, b = r >> 2, j = r & 3;
    ws[OFF_HT4_0 + idx] = z[b * 1024 + (q << 2) + j];
  }
  if (idx < 8192) ws[OFF_PART + idx] = (idx & 1) ? 0.f : -FLT_MAX;
  if (idx < 256) ((unsigned*)(ws + OFF_BAR))[idx] = 0u;
}

// ---------------------------------------------------------------------------
// Hierarchical device-scope grid barrier: 8 sub-counters (32 blocks each,
// separate cache lines) -> 1 master -> generation bump. Proven in rounds 1-2.
// ---------------------------------------------------------------------------
__device__ __forceinline__ void gbar(unsigned* bar, int bid) {
  __syncthreads();
  if (threadIdx.x == 0) {
    unsigned* gen = bar + 160;
    unsigned g = __hip_atomic_load(gen, __ATOMIC_RELAXED, __HIP_MEMORY_SCOPE_AGENT);
    unsigned* c = bar + ((bid & 7) << 4);
    unsigned a = __hip_atomic_fetch_add(c, 1u, __ATOMIC_ACQ_REL, __HIP_MEMORY_SCOPE_AGENT);
    bool done = false;
    if (a == 31u) {
      __hip_atomic_store(c, 0u, __ATOMIC_RELAXED, __HIP_MEMORY_SCOPE_AGENT);
      unsigned m = __hip_atomic_fetch_add(bar + 128, 1u, __ATOMIC_ACQ_REL,
                                          __HIP_MEMORY_SCOPE_AGENT);
      if (m == 7u) {
        __hip_atomic_store(bar + 128, 0u, __ATOMIC_RELAXED, __HIP_MEMORY_SCOPE_AGENT);
        __hip_atomic_fetch_add(gen, 1u, __ATOMIC_RELEASE, __HIP_MEMORY_SCOPE_AGENT);
        done = true;
      }
    }
    if (!done) {
      while (__hip_atomic_load(gen, __ATOMIC_RELAXED, __HIP_MEMORY_SCOPE_AGENT) == g)
        __builtin_amdgcn_s_sleep(2);
    }
    __builtin_amdgcn_fence(__ATOMIC_ACQUIRE, "agent");
  }
  __syncthreads();
}

// ---------------------------------------------------------------------------
// Persistent kernel, 256 blocks x 1024 threads (16 waves, 4 waves/SIMD).
// Block owns units blk*4..+3 (16 w_hh rows resident in LDS, +4-float row pad).
// Per step, h(t-1) is STREAMED THROUGH LDS in 32 double-buffered chunks of
// 8 q-rows (32 KB) + the block's w_lin chunk slice (4 KB), register-staged
// global->LDS. Global h traffic: 1 MB/CU/step (was 4 MB via L1 in r2).
//   gates: wave=(rg=unit, bg=b-group); lane=b; acc[4 gates] -> the LSTM cell
//          update is LANE-LOCAL (no k-split, no LDS exchange, c in register).
//          h reads: contiguous wave-wide b128; w_hh reads: uniform broadcast.
//   head:  wave=batch (bc*16+wid); lane=(ks k-half, ol o); h read is a
//          wave-uniform LDS broadcast from the same chunk; w_lin from the
//          co-staged slice; shfl ks-reduce + shfl argmax -> partials.
// 2 grid barriers/step (argmax partials ready; h(t) ready).
// ---------------------------------------------------------------------------
__global__ __launch_bounds__(1024, 4) void k_persist(
    const float* __restrict__ w_hh, const float* __restrict__ w_ih,
    const float* __restrict__ b_ih, const float* __restrict__ b_hh,
    const float* __restrict__ b_lin, float* __restrict__ out,
    float* __restrict__ ws) {
  __shared__ float wlds[16 * 1028];   // resident w_hh rows, padded (65.8 KB)
  __shared__ float buf[2][9216];      // chunk: h 8192 + w_lin slice 1024 (2x36 KB)

  const int tid = threadIdx.x;
  const int blk = blockIdx.x;
  const int lane = tid & 63;
  const int wid = tid >> 6;           // wave 0..15

  // gates mapping: wave = (rg = unit-within-block, bg = 64-batch group)
  const int rg = wid & 3;
  const int bgw = wid >> 2;
  const int gb = (bgw << 6) + lane;   // this lane's batch (0..255)

  // head mapping: block = (bc 16 batches, oc 32 outputs); wave = one batch
  const int oc = blk & 15, bc = blk >> 4;
  const int hbb = (bc << 4) + wid;    // head wave's batch
  const int ks = lane >> 5, ol = lane & 31;
  const int oo = (oc << 5) + ol;

  unsigned* bar = (unsigned*)(ws + OFF_BAR);
  float* part = ws + OFF_PART;
  const float* wlt = ws + OFF_WLT;

  // ---- one-time: stage 16 w_hh rows (row r=uu*4+g <- w_hh[g*1024 + blk*4+uu])
#pragma unroll
  for (int i = 0; i < 4; ++i) {
    int idx = (i << 10) + tid;        // 0..4095 float4s
    int r = idx >> 8, c4 = idx & 255;
    int grow = ((r & 3) << 10) + (blk << 2) + (r >> 2);
    *(float4*)(&wlds[r * 1028 + (c4 << 2)]) =
        *(const float4*)(w_hh + ((long)grow << 10) + (c4 << 2));
  }

  // ---- per-lane cell-update constants: unit ue = blk*4+rg (wave-uniform)
  const int ue = (blk << 2) + rg;
  const float bi_ = b_ih[ue] + b_hh[ue];
  const float bf_ = b_ih[1024 + ue] + b_hh[1024 + ue];
  const float bg_ = b_ih[2048 + ue] + b_hh[2048 + ue];
  const float bo_ = b_ih[3072 + ue] + b_hh[3072 + ue];
  const float wi_ = w_ih[ue], wf_ = w_ih[1024 + ue];
  const float wg_ = w_ih[2048 + ue], wo_ = w_ih[3072 + ue];
  float creg = 0.f;                   // c-state for (ue, gb), register-resident

  // ---- head constants
  const float blr = b_lin[oo];
  float* outp = out + (long)hbb * (NT * NO) + oo;

  const float* wr0 = &wlds[((rg << 2) + 0) * 1028];
  const float* wr1 = &wlds[((rg << 2) + 1) * 1028];
  const float* wr2 = &wlds[((rg << 2) + 2) * 1028];
  const float* wr3 = &wlds[((rg << 2) + 3) * 1028];

  __syncthreads();

  for (int t = 0; t <= NT; ++t) {
    const float* hin = ws + ((t & 1) ? OFF_HT4_1 : OFF_HT4_0);   // h(t-1)
    float* hout = ws + ((t & 1) ? OFF_HT4_0 : OFF_HT4_1);        // h(t)

    // ---- prologue: stage chunk 0 (wave stages 2x1KB h segs; waves 8-15 w_lin)
    {
      float4 s0 = *(const float4*)(hin + (((wid << 1) + 0) << 8) + (lane << 2));
      float4 s1 = *(const float4*)(hin + (((wid << 1) + 1) << 8) + (lane << 2));
      *(float4*)(&buf[0][(((wid << 1) + 0) << 8) + (lane << 2)]) = s0;
      *(float4*)(&buf[0][(((wid << 1) + 1) << 8) + (lane << 2)]) = s1;
      if (wid >= 8 && lane < 32) {
        float4 sw = *(const float4*)(wlt + ((wid - 8) << 11) + (oc << 7) + (lane << 2));
        *(float4*)(&buf[0][8192 + ((wid - 8) << 7) + (lane << 2)]) = sw;
      }
      __syncthreads();
    }

    float a0 = 0.f, a1 = 0.f, a2 = 0.f, a3 = 0.f;  // gate dots for (ue, gb)
    float ha = 0.f;                                 // head partial (hbb, oo, ks)

    for (int c = 0; c < 32; ++c) {
      float4 s0, s1, sw;
      const bool more = (c < 31);
      if (more) {                     // issue next-chunk global loads early
        const float* src = hin + ((c + 1) << 13);
        s0 = *(const float4*)(src + (((wid << 1) + 0) << 8) + (lane << 2));
        s1 = *(const float4*)(src + (((wid << 1) + 1) << 8) + (lane << 2));
        if (wid >= 8 && lane < 32)
          sw = *(const float4*)(wlt + ((((c + 1) << 3) + (wid - 8)) << 11) +
                                (oc << 7) + (lane << 2));
      }
      const float* bh = buf[c & 1];
      const float* bw = bh + 8192;
      const int kof = c << 5;
      // gates: 8 q-rows; h b128 contiguous per wave; w broadcast from LDS
#pragma unroll
      for (int qq = 0; qq < 8; ++qq) {
        const float4 h4 = *(const float4*)(bh + (qq << 10) + (gb << 2));
        const float4 w0 = *(const float4*)(wr0 + kof + (qq << 2));
        const float4 w1 = *(const float4*)(wr1 + kof + (qq << 2));
        const float4 w2 = *(const float4*)(wr2 + kof + (qq << 2));
        const float4 w3 = *(const float4*)(wr3 + kof + (qq << 2));
        FMA4(a0, w0, h4); FMA4(a1, w1, h4);
        FMA4(a2, w2, h4); FMA4(a3, w3, h4);
      }
      // head: this lane's k-half of the chunk (4 q-rows); h uniform broadcast
#pragma unroll
      for (int g2 = 0; g2 < 4; ++g2) {
        const int qq = (ks << 2) + g2;
        const float4 h4 = *(const float4*)(bh + (qq << 10) + (hbb << 2));
        const float4 w4 = *(const float4*)(bw + (qq << 7) + (ol << 2));
        FMA4(ha, w4, h4);
      }
      if (more) {                     // write staged regs into the other buffer
        float* db = buf[(c + 1) & 1];
        *(float4*)(&db[(((wid << 1) + 0) << 8) + (lane << 2)]) = s0;
        *(float4*)(&db[(((wid << 1) + 1) << 8) + (lane << 2)]) = s1;
        if (wid >= 8 && lane < 32)
          *(float4*)(&db[8192 + ((wid - 8) << 7) + (lane << 2)]) = sw;
      }
      __syncthreads();                // single barrier per chunk
    }

    // ---- head finalize (t>0): ks-pair reduce, out write, argmax partial
    if (t > 0) {
      float v2 = ha + __shfl_xor(ha, 32, 64);
      if (ks == 0) {                  // lanes 0..31 hold the full dot for oo
        const float a = v2 + blr;
        outp[(long)(t - 1) << 9] = a;
        float v = a, io = (float)oo;  // strict >, min index on ties
#pragma unroll
        for (int m = 16; m >= 1; m >>= 1) {
          const float vo = __shfl_xor(v, m, 64);
          const float ioo = __shfl_xor(io, m, 64);
          if (vo > v || (vo == v && ioo < io)) { v = vo; io = ioo; }
        }
        if (ol == 0)
          *(float2*)(part + (hbb << 5) + (oc << 1)) = make_float2(v, io);
      }
    }
    if (t == NT) break;
    gbar(bar, blk);

    // ---- epilogue: lane-local LSTM cell update for (ue, gb)
    {
      // combine 16 argmax partials (ascending o-chunk, strict > => first wins)
      const float* pb = part + (gb << 5);
      float4 p0 = *(const float4*)(pb);
      float v = p0.x, ix = p0.y;
      if (p0.z > v) { v = p0.z; ix = p0.w; }
#pragma unroll
      for (int cc = 1; cc < 8; ++cc) {
        float4 p2 = *(const float4*)(pb + (cc << 2));
        if (p2.x > v) { v = p2.x; ix = p2.y; }
        if (p2.z > v) { v = p2.z; ix = p2.w; }
      }
      const float xb = ix;
      const float gi = a0 + bi_ + xb * wi_;
      const float gf = a1 + bf_ + xb * wf_;
      const float gg = a2 + bg_ + xb * wg_;
      const float go = a3 + bo_ + xb * wo_;
      // accurate expf/tanhf: argmax feedback needs ~1e-6 accuracy
      const float cn = sigf(gf) * creg + sigf(gi) * tanhf(gg);
      const float hn = sigf(go) * tanhf(cn);
      creg = cn;
      hout[(blk << 10) + (gb << 2) + rg] = hn;   // hT4[q=blk][b=gb][j=rg]
    }
    gbar(bar, blk);
  }
}

extern "C" void kernel_launch(void* const* d_in, const int* in_sizes, int n_in,
                              void* d_out, int out_size, void* d_ws, size_t ws_size,
                              hipStream_t stream) {
  (void)in_sizes; (void)n_in; (void)out_size; (void)ws_size;
  const float* z     = (const float*)d_in[0];
  const float* w_ih  = (const float*)d_in[1];
  const float* w_hh  = (const float*)d_in[2];
  const float* b_ih  = (const float*)d_in[3];
  const float* b_hh  = (const float*)d_in[4];
  const float* w_lin = (const float*)d_in[5];
  const float* b_lin = (const float*)d_in[6];
  float* out = (float*)d_out;
  float* ws  = (float*)d_ws;

  k_init<<<2048, 256, 0, stream>>>(z, w_lin, ws);

  void* args[] = {(void*)&w_hh, (void*)&w_ih, (void*)&b_ih, (void*)&b_hh,
                  (void*)&b_lin, (void*)&out, (void*)&ws};
  hipLaunchCooperativeKernel((const void*)k_persist, dim3(256), dim3(1024),
                             args, 0, stream);
}

// Round 5
// 42323.273 us; speedup vs baseline: 11.4153x; 11.4153x over previous
//
#include <hip/hip_runtime.h>
#include <math.h>
#include <float.h>

// Problem: B=256, H=1024, I=1, O=512, T=512. Autoregressive LSTM + greedy head.
#define NB 256
#define NH 1024
#define NO 512
#define NT 512

// ---------------- workspace layout (float offsets) ----------------
// hT4 layout: [q=u>>2][b][j=u&3]  (256K floats per buffer). Block blk owns q=blk.
#define OFF_HT4_0 0
#define OFF_HT4_1 (256*1024)
#define OFF_WLT   (2*256*1024)            // packed w_lin: [u/4][o][4] = 512K floats
#define OFF_PART  (OFF_WLT + 512*1024)    // argmax partials [B][16][{val,idx}] = 8192
#define OFF_BAR   (OFF_PART + 8192)       // barrier: cnt8 @ dword i*16, master @128, gen @160

__device__ __forceinline__ float sigf(float x) { return 1.f / (1.f + expf(-x)); }

#define FMA4(A, W, H4) \
  A = fmaf((W).x, (H4).x, A); A = fmaf((W).y, (H4).y, A); \
  A = fmaf((W).z, (H4).z, A); A = fmaf((W).w, (H4).w, A);

// ---------------------------------------------------------------------------
// Init: pack h0=z into hT4 ping, pack w_lin into [u/4][o][4], seed argmax
// partials to (-FLT_MAX, 0) so step 0 sees xin = 0, zero barrier state.
// (c-state lives in registers of the persistent kernel.)
// ---------------------------------------------------------------------------
__global__ void k_init(const float* __restrict__ z, const float* __restrict__ w_lin,
                       float* __restrict__ ws) {
  int idx = blockIdx.x * 256 + threadIdx.x;
  if (idx < 512 * 1024) {                 // wltp[uq*2048 + o*4 + j] = w_lin[o][4uq+j]
    int j = idx & 3, o = (idx >> 2) & 511, uq = idx >> 11;
    ws[OFF_WLT + idx] = w_lin[o * 1024 + (uq << 2) + j];
  }
  if (idx < 256 * 1024) {                 // hT4[q][b][j] = z[b][4q+j]
    int q = idx >> 10, r = idx & 1023, b = r >> 2, j = r & 3;
    ws[OFF_HT4_0 + idx] = z[b * 1024 + (q << 2) + j];
  }
  if (idx < 8192) ws[OFF_PART + idx] = (idx & 1) ? 0.f : -FLT_MAX;
  if (idx < 256) ((unsigned*)(ws + OFF_BAR))[idx] = 0u;
}

// ---------------------------------------------------------------------------
// Hierarchical device-scope grid barrier: 8 sub-counters (32 blocks each,
// separate cache lines) -> 1 master -> generation bump. Proven in rounds 1-3.
// ---------------------------------------------------------------------------
__device__ __forceinline__ void gbar(unsigned* bar, int bid) {
  __syncthreads();
  if (threadIdx.x == 0) {
    unsigned* gen = bar + 160;
    unsigned g = __hip_atomic_load(gen, __ATOMIC_RELAXED, __HIP_MEMORY_SCOPE_AGENT);
    unsigned* c = bar + ((bid & 7) << 4);
    unsigned a = __hip_atomic_fetch_add(c, 1u, __ATOMIC_ACQ_REL, __HIP_MEMORY_SCOPE_AGENT);
    bool done = false;
    if (a == 31u) {
      __hip_atomic_store(c, 0u, __ATOMIC_RELAXED, __HIP_MEMORY_SCOPE_AGENT);
      unsigned m = __hip_atomic_fetch_add(bar + 128, 1u, __ATOMIC_ACQ_REL,
                                          __HIP_MEMORY_SCOPE_AGENT);
      if (m == 7u) {
        __hip_atomic_store(bar + 128, 0u, __ATOMIC_RELAXED, __HIP_MEMORY_SCOPE_AGENT);
        __hip_atomic_fetch_add(gen, 1u, __ATOMIC_RELEASE, __HIP_MEMORY_SCOPE_AGENT);
        done = true;
      }
    }
    if (!done) {
      while (__hip_atomic_load(gen, __ATOMIC_RELAXED, __HIP_MEMORY_SCOPE_AGENT) == g)
        __builtin_amdgcn_s_sleep(2);
    }
    __builtin_amdgcn_fence(__ATOMIC_ACQUIRE, "agent");
  }
  __syncthreads();
}

// ---------------------------------------------------------------------------
// Persistent kernel, 256 blocks x 1024 threads (16 waves, 4 waves/SIMD).
// Block owns units blk*4..+3; 16 w_hh gate rows resident in LDS (64 KB,
// staged once for all 512 steps). Per step:
//   gates: wave (rg = wid>>3: 2 units = 8 rows; kq = wid&7: k-eighth).
//          acc[8 rows][4 batch-cols]; h f4 from GLOBAL (L1/L2, 2 MB/CU/step,
//          double-buffered in regs within the loop only -- nothing lives
//          across barriers); w f4 broadcast from LDS. 8-way k-reduce via
//          64 KB LDS exchange (kq<4 write; kq>=4 read-add-write).
//   head:  wave (kh = k-eighth, bh = batch-half); lane = (bsel, o); 4 batches
//          per lane (ABSOLUTE batch base bc*16 -- r4 bug was missing this);
//          w_lin packed f4 stream (L2); 8-way reduce via 16 KB hx;
//          tid<512 finalize: out write + shfl argmax -> part.
//   gbar -> epilogue: thread (uu=tid&3, be=tid>>2): xin from part, gate sums
//          from ex, register c-state, fully coalesced h(t) write -> gbar.
// ---------------------------------------------------------------------------
__global__ __launch_bounds__(1024, 4) void k_persist(
    const float* __restrict__ w_hh, const float* __restrict__ w_ih,
    const float* __restrict__ b_ih, const float* __restrict__ b_hh,
    const float* __restrict__ b_lin, float* __restrict__ out,
    float* __restrict__ ws) {
  __shared__ float wlds[16 * 1024];   // resident w_hh rows (64 KB)
  __shared__ float ex[4 * 4096];      // gates k-split exchange (64 KB)
  __shared__ float hx[8 * 512];       // head k-split partials (16 KB)

  const int tid = threadIdx.x;
  const int blk = blockIdx.x;
  const int lane = tid & 63;
  const int wid = tid >> 6;           // wave 0..15

  // gates mapping
  const int rg = wid >> 3;            // 0..1: rows rg*8 .. rg*8+7
  const int kq = wid & 7;             // k-eighth: q in [kq*32, kq*32+32)

  // head mapping: block = (bc = blk>>4 -> 16 batches, oc = blk&15 -> 32 o's)
  const int oc = blk & 15, bc = blk >> 4;
  const int kh = wid & 7, bh = wid >> 3;
  const int bsel = lane >> 5, ol = lane & 31;

  unsigned* bar = (unsigned*)(ws + OFF_BAR);
  float* part = ws + OFF_PART;
  const float* wlt = ws + OFF_WLT;

  // ---- one-time: stage 16 w_hh rows (row r=uu*4+g <- w_hh[g*1024 + blk*4+uu])
#pragma unroll
  for (int i = 0; i < 4; ++i) {
    int idx = (i << 10) + tid;        // 0..4095 float4s
    int r = idx >> 8, c4 = idx & 255;
    int grow = ((r & 3) << 10) + (blk << 2) + (r >> 2);
    *(float4*)(&wlds[(r << 10) + (c4 << 2)]) =
        *(const float4*)(w_hh + ((long)grow << 10) + (c4 << 2));
  }

  // ---- epilogue constants: thread owns (unit uu, batch be); mapping gives a
  // fully coalesced h-state write hnext[blk*1024 + tid].
  const int uu = tid & 3;
  const int be = tid >> 2;
  const int ue = (blk << 2) + uu;
  const float bi_ = b_ih[ue] + b_hh[ue];
  const float bf_ = b_ih[1024 + ue] + b_hh[1024 + ue];
  const float bg_ = b_ih[2048 + ue] + b_hh[2048 + ue];
  const float bo_ = b_ih[3072 + ue] + b_hh[3072 + ue];
  const float wi_ = w_ih[ue], wf_ = w_ih[1024 + ue];
  const float wg_ = w_ih[2048 + ue], wo_ = w_ih[3072 + ue];
  float creg = 0.f;                   // c-state for (ue, be), register-resident

  // ---- head constants (finalize mapping, tid<512: bl=tid>>5, ol2=tid&31)
  const int oo = (oc << 5) + (tid & 31);
  const int ob = (bc << 4) + (tid >> 5);
  const float blr = b_lin[(oc << 5) + (tid & 31)];
  float* outp = out + (long)ob * (NT * NO) + oo;

  const float* wrow = &wlds[rg << 13];          // 8 rows, stride 1024

  __syncthreads();

  for (int t = 0; t <= NT; ++t) {
    const float* hin = ws + ((t & 1) ? OFF_HT4_1 : OFF_HT4_0);   // h(t-1)
    float* hout = ws + ((t & 1) ? OFF_HT4_0 : OFF_HT4_1);        // h(t)

    if (t < NT) {
      // ============ gates(t): 8 rows x 4 b-cols x k-eighth ============
      float acc[8][4];
#pragma unroll
      for (int j = 0; j < 8; ++j)
#pragma unroll
        for (int bb = 0; bb < 4; ++bb) acc[j][bb] = 0.f;

      const float* hq = hin + ((kq << 5) << 10) + (lane << 2);
      float4 hA[4], hB[4];
#pragma unroll
      for (int bb = 0; bb < 4; ++bb) hA[bb] = *(const float4*)(hq + (bb << 8));

      for (int qi = 0; qi < 32; qi += 2) {
        if ((qi & 7) == 0) __builtin_amdgcn_s_barrier();  // lockstep -> L1 reuse
#pragma unroll
        for (int bb = 0; bb < 4; ++bb)
          hB[bb] = *(const float4*)(hq + ((qi + 1) << 10) + (bb << 8));
        {
          const int ko = ((kq << 5) + qi) << 2;
#pragma unroll
          for (int j = 0; j < 8; ++j) {
            const float4 wv = *(const float4*)(wrow + (j << 10) + ko);
            FMA4(acc[j][0], wv, hA[0]); FMA4(acc[j][1], wv, hA[1]);
            FMA4(acc[j][2], wv, hA[2]); FMA4(acc[j][3], wv, hA[3]);
          }
        }
        if (qi + 2 < 32) {
#pragma unroll
          for (int bb = 0; bb < 4; ++bb)
            hA[bb] = *(const float4*)(hq + ((qi + 2) << 10) + (bb << 8));
        }
        {
          const int ko = ((kq << 5) + qi + 1) << 2;
#pragma unroll
          for (int j = 0; j < 8; ++j) {
            const float4 wv = *(const float4*)(wrow + (j << 10) + ko);
            FMA4(acc[j][0], wv, hB[0]); FMA4(acc[j][1], wv, hB[1]);
            FMA4(acc[j][2], wv, hB[2]); FMA4(acc[j][3], wv, hB[3]);
          }
        }
      }

      // ---- 8-way k-reduce via LDS exchange: ex[p][row][b]
      if (kq < 4) {
#pragma unroll
        for (int j = 0; j < 8; ++j)
#pragma unroll
          for (int bb = 0; bb < 4; ++bb)
            ex[(kq << 12) + (((rg << 3) + j) << 8) + (bb << 6) + lane] = acc[j][bb];
      }
      __syncthreads();
      if (kq >= 4) {
        const int p = kq & 3;
#pragma unroll
        for (int j = 0; j < 8; ++j)
#pragma unroll
          for (int bb = 0; bb < 4; ++bb) {
            const int a = (p << 12) + (((rg << 3) + j) << 8) + (bb << 6) + lane;
            ex[a] += acc[j][bb];
          }
      }
      __syncthreads();
    }

    if (t > 0) {
      // ============ head(t-1): x = h(t-1) @ w_lin^T + b_lin ============
      float ah[4] = {0.f, 0.f, 0.f, 0.f};
      const float* hh = hin + ((kh << 5) << 10);
      const float* wl = wlt + ((kh << 5) << 11) + (((oc << 5) + ol) << 2);
#pragma unroll 2
      for (int qi = 0; qi < 32; ++qi) {
        const float4 wv = *(const float4*)(wl + (qi << 11));
#pragma unroll
        for (int bb = 0; bb < 4; ++bb) {
          // ABSOLUTE batch = bc*16 + local (r4 bug: bc*16 base was missing)
          const float4 hv = *(const float4*)(
              hh + (qi << 10) + (((bc << 4) + (bh << 3) + (bsel << 2) + bb) << 2));
          FMA4(ah[bb], wv, hv);
        }
      }
#pragma unroll
      for (int bb = 0; bb < 4; ++bb)
        hx[(kh << 9) + (((bh << 3) + (bsel << 2) + bb) << 5) + ol] = ah[bb];
      __syncthreads();
      if (tid < 512) {
        float a = blr;
#pragma unroll
        for (int kk = 0; kk < 8; ++kk) a += hx[(kk << 9) + tid];
        outp[(long)(t - 1) << 9] = a;
        // argmax over this 32-o chunk (strict >, min index on ties)
        float v = a, io = (float)oo;
#pragma unroll
        for (int m = 16; m >= 1; m >>= 1) {
          const float vo = __shfl_xor(v, m, 64);
          const float ioo = __shfl_xor(io, m, 64);
          if (vo > v || (vo == v && ioo < io)) { v = vo; io = ioo; }
        }
        if ((tid & 31) == 0)
          *(float2*)(part + (ob << 5) + (oc << 1)) = make_float2(v, io);
      }
    }
    if (t == NT) break;

    gbar(bar, blk);

    // ============ epilogue(t): lane-local LSTM cell update ============
    {
      // combine 16 argmax partials (ascending o-chunk, strict > => first wins)
      const float* pb = part + (be << 5);
      float4 p0 = *(const float4*)(pb);
      float v = p0.x, ix = p0.y;
      if (p0.z > v) { v = p0.z; ix = p0.w; }
#pragma unroll
      for (int cc = 1; cc < 8; ++cc) {
        float4 p2 = *(const float4*)(pb + (cc << 2));
        if (p2.x > v) { v = p2.x; ix = p2.y; }
        if (p2.z > v) { v = p2.z; ix = p2.w; }
      }
      const float xb = ix;
      float s[4];
#pragma unroll
      for (int g = 0; g < 4; ++g) {
        const int rowoff = (((uu << 2) + g) << 8) + be;
        s[g] = ex[rowoff] + ex[4096 + rowoff] + ex[8192 + rowoff] + ex[12288 + rowoff];
      }
      const float gi = s[0] + bi_ + xb * wi_;
      const float gf = s[1] + bf_ + xb * wf_;
      const float gg = s[2] + bg_ + xb * wg_;
      const float go = s[3] + bo_ + xb * wo_;
      // accurate expf/tanhf: argmax feedback needs ~1e-6 accuracy
      const float cn = sigf(gf) * creg + sigf(gi) * tanhf(gg);
      const float hn = sigf(go) * tanhf(cn);
      creg = cn;
      hout[(blk << 10) + tid] = hn;   // hT4[q=blk][b=be][j=uu], coalesced
    }
    gbar(bar, blk);
  }
}

extern "C" void kernel_launch(void* const* d_in, const int* in_sizes, int n_in,
                              void* d_out, int out_size, void* d_ws, size_t ws_size,
                              hipStream_t stream) {
  (void)in_sizes; (void)n_in; (void)out_size; (void)ws_size;
  const float* z     = (const float*)d_in[0];
  const float* w_ih  = (const float*)d_in[1];
  const float* w_hh  = (const float*)d_in[2];
  const float* b_ih  = (const float*)d_in[3];
  const float* b_hh  = (const float*)d_in[4];
  const float* w_lin = (const float*)d_in[5];
  const float* b_lin = (const float*)d_in[6];
  float* out = (float*)d_out;
  float* ws  = (float*)d_ws;

  k_init<<<2048, 256, 0, stream>>>(z, w_lin, ws);

  void* args[] = {(void*)&w_hh, (void*)&w_ih, (void*)&b_ih, (void*)&b_hh,
                  (void*)&b_lin, (void*)&out, (void*)&ws};
  hipLaunchCooperativeKernel((const void*)k_persist, dim3(256), dim3(1024),
                             args, 0, stream);
}